// Round 1
// baseline (485.008 us; speedup 1.0000x reference)
//
#include <hip/hip_runtime.h>

#define B_  8
#define P_  21
#define H_  32
#define W_  32

// ---------------------------------------------------------------- CSR build
struct CsrParams {
  const int*   row[4];
  const int*   col[4];
  const float* val[4];
  int*   cnt[4];
  int*   rowptr[4];
  int*   colsout[4];
  float* valsout[4];
  int    nnz[4];
  int    V[4];
};

__global__ void count_kernel(CsrParams p) {
  int l = blockIdx.y;
  int k = blockIdx.x * 256 + threadIdx.x;
  if (k < p.nnz[l]) atomicAdd(&p.cnt[l][p.row[l][k]], 1);
}

__global__ void scan_kernel(CsrParams p) {
  int l = blockIdx.x;
  int V = p.V[l];
  int* cnt = p.cnt[l];
  int* rp  = p.rowptr[l];
  int t = threadIdx.x;
  int chunk = V / 256;            // 4,8,16,32 — exact
  int base = t * chunk;
  int s = 0;
  for (int i = 0; i < chunk; ++i) s += cnt[base + i];
  __shared__ int sm[256];
  sm[t] = s;
  __syncthreads();
  for (int off = 1; off < 256; off <<= 1) {
    int v = (t >= off) ? sm[t - off] : 0;
    __syncthreads();
    sm[t] += v;
    __syncthreads();
  }
  int run = sm[t] - s;            // exclusive prefix
  for (int i = 0; i < chunk; ++i) {
    int c = cnt[base + i];
    rp[base + i]  = run;
    cnt[base + i] = run;          // becomes fill cursor
    run += c;
  }
  if (t == 255) rp[V] = run;      // == nnz
}

__global__ void fill_kernel(CsrParams p) {
  int l = blockIdx.y;
  int k = blockIdx.x * 256 + threadIdx.x;
  if (k < p.nnz[l]) {
    int r = p.row[l][k];
    int pos = atomicAdd(&p.cnt[l][r], 1);
    p.colsout[l][pos] = p.col[l][k];
    p.valsout[l][pos] = p.val[l][k];
  }
}

// ---------------------------------------------------------------- sampling
__global__ void sample_kernel(const float* __restrict__ uv,
                              const float* __restrict__ feat,
                              float* __restrict__ xs) {
  int bp = blockIdx.x;            // b*21+p
  int b  = bp / P_;
  float u0 = uv[bp * 2 + 0], u1 = uv[bp * 2 + 1];
  float gx = fminf(fmaxf((u0 - 0.5f) * 2.0f, -1.0f), 1.0f);
  float gy = fminf(fmaxf((u1 - 0.5f) * 2.0f, -1.0f), 1.0f);
  float fx = (gx + 1.0f) * 0.5f * (W_ - 1);
  float fy = (gy + 1.0f) * 0.5f * (H_ - 1);
  float x0f = floorf(fx), y0f = floorf(fy);
  float wx = fx - x0f, wy = fy - y0f;
  int x0 = (int)x0f, y0 = (int)y0f;
  int x0i = min(max(x0, 0), W_ - 1), x1i = min(max(x0 + 1, 0), W_ - 1);
  int y0i = min(max(y0, 0), H_ - 1), y1i = min(max(y0 + 1, 0), H_ - 1);
  float w00 = (1.f - wy) * (1.f - wx), w01 = (1.f - wy) * wx;
  float w10 = wy * (1.f - wx),        w11 = wy * wx;
  for (int c = threadIdx.x; c < 512; c += blockDim.x) {
    const float* fb = feat + ((size_t)(b * 512 + c)) * (H_ * W_);
    float v = fb[y0i * W_ + x0i] * w00 + fb[y0i * W_ + x1i] * w01 +
              fb[y1i * W_ + x0i] * w10 + fb[y1i * W_ + x1i] * w11;
    xs[(size_t)bp * 512 + c] = v;
  }
}

__global__ void upsample_kernel(const float* __restrict__ up,
                                const float* __restrict__ xs,
                                float* __restrict__ xu) {
  int v = blockIdx.x, b = blockIdx.y;
  int c4 = threadIdx.x << 2;      // 128 threads * 4 = 512
  float4 acc = make_float4(0.f, 0.f, 0.f, 0.f);
  for (int p = 0; p < P_; ++p) {
    float u = up[v * P_ + p];
    const float4 xv = *(const float4*)&xs[((size_t)(b * P_ + p)) * 512 + c4];
    acc.x = fmaf(u, xv.x, acc.x);
    acc.y = fmaf(u, xv.y, acc.y);
    acc.z = fmaf(u, xv.z, acc.z);
    acc.w = fmaf(u, xv.w, acc.w);
  }
  *(float4*)&xu[((size_t)(b * 512 + v)) * 512 + c4] = acc;
}

// ---------------------------------------------------------------- pool (CSR gather)
__global__ void pool_kernel(const float* __restrict__ x,
                            const int* __restrict__ rowptr,
                            const int* __restrict__ cols,
                            const float* __restrict__ vals,
                            float* __restrict__ out,
                            int Vout, int Vin, int Cin) {
  int lanes = Cin >> 2;
  int lshift = 31 - __clz(lanes);
  int rpb = 128 >> lshift;
  int lr = threadIdx.x >> lshift;
  int lc = threadIdx.x & (lanes - 1);
  int n = blockIdx.x * rpb + lr;
  int b = blockIdx.y;
  int c4 = lc << 2;
  int j0 = rowptr[n], j1 = rowptr[n + 1];
  float4 acc = make_float4(0.f, 0.f, 0.f, 0.f);
  for (int j = j0; j < j1; ++j) {
    int src = cols[j];
    float v = vals[j];
    const float4 xv = *(const float4*)&x[((size_t)b * Vin + src) * Cin + c4];
    acc.x = fmaf(v, xv.x, acc.x);
    acc.y = fmaf(v, xv.y, acc.y);
    acc.z = fmaf(v, xv.z, acc.z);
    acc.w = fmaf(v, xv.w, acc.w);
  }
  *(float4*)&out[((size_t)b * Vout + n) * Cin + c4] = acc;
}

// ---------------------------------------------------------------- depthwise gather
__global__ void dw_kernel(const float* __restrict__ xin,
                          const int* __restrict__ sidx,
                          const float* __restrict__ wd,
                          float* __restrict__ out,
                          int Vout, int Cin) {
  int lanes = Cin >> 2;
  int lshift = 31 - __clz(lanes);
  int rpb = 128 >> lshift;
  int lr = threadIdx.x >> lshift;
  int lc = threadIdx.x & (lanes - 1);
  int n = blockIdx.x * rpb + lr;
  int b = blockIdx.y;
  int c4 = lc << 2;
  float4 acc = make_float4(0.f, 0.f, 0.f, 0.f);
  #pragma unroll
  for (int s = 0; s < 9; ++s) {
    int r = sidx[n * 9 + s];
    const float4 wv = *(const float4*)&wd[s * Cin + c4];
    const float4 xv = *(const float4*)&xin[((size_t)b * Vout + r) * Cin + c4];
    acc.x = fmaf(wv.x, xv.x, acc.x);
    acc.y = fmaf(wv.y, xv.y, acc.y);
    acc.z = fmaf(wv.z, xv.z, acc.z);
    acc.w = fmaf(wv.w, xv.w, acc.w);
  }
  *(float4*)&out[((size_t)b * Vout + n) * Cin + c4] = acc;
}

// ---------------------------------------------------------------- fp32 GEMM + bias (+relu)
template <int BM, int BN, int BK, int TM, int TN, bool RELU>
__launch_bounds__(256)
__global__ void gemm_bias(const float* __restrict__ A,   // M x K
                          const float* __restrict__ Bw,  // K x N
                          const float* __restrict__ bias,
                          float* __restrict__ C,         // M x N
                          int M, int N, int K) {
  static_assert(TM == 8, "TM fixed at 8");
  constexpr int TMH = TM / 2;
  constexpr int TNH = TN / 2;
  constexpr int NTX = BN / TN;     // 16 for both configs
  __shared__ float As[BK][BM + 4];
  __shared__ float Bs[BK][BN];
  const int tid   = threadIdx.x;
  const int col_t = tid % NTX;
  const int row_t = tid / NTX;
  const int m0 = blockIdx.x * BM;
  const int n0 = blockIdx.y * BN;

  float acc[TM][TN];
  #pragma unroll
  for (int i = 0; i < TM; ++i)
    #pragma unroll
    for (int j = 0; j < TN; ++j) acc[i][j] = 0.f;

  for (int k0 = 0; k0 < K; k0 += BK) {
    // stage A tile (transpose into As[k][m])
    #pragma unroll
    for (int l = tid; l < BM * BK / 4; l += 256) {
      int row = l >> 2;           // BK/4 == 4
      int kq  = l & 3;
      const float4 v = *(const float4*)&A[(size_t)(m0 + row) * K + k0 + (kq << 2)];
      As[kq * 4 + 0][row] = v.x;
      As[kq * 4 + 1][row] = v.y;
      As[kq * 4 + 2][row] = v.z;
      As[kq * 4 + 3][row] = v.w;
    }
    // stage B tile (direct)
    #pragma unroll
    for (int l = tid; l < BK * BN / 4; l += 256) {
      int row = l / (BN / 4);
      int cq  = l % (BN / 4);
      *(float4*)&Bs[row][cq * 4] =
          *(const float4*)&Bw[(size_t)(k0 + row) * N + n0 + cq * 4];
    }
    __syncthreads();
    #pragma unroll
    for (int kk = 0; kk < BK; ++kk) {
      float a[TM], b[TN];
      const float4 a0 = *(const float4*)&As[kk][row_t * TMH];
      const float4 a1 = *(const float4*)&As[kk][BM / 2 + row_t * TMH];
      a[0] = a0.x; a[1] = a0.y; a[2] = a0.z; a[3] = a0.w;
      a[4] = a1.x; a[5] = a1.y; a[6] = a1.z; a[7] = a1.w;
      if constexpr (TNH == 4) {
        const float4 b0 = *(const float4*)&Bs[kk][col_t * 4];
        const float4 b1 = *(const float4*)&Bs[kk][BN / 2 + col_t * 4];
        b[0] = b0.x; b[1] = b0.y; b[2] = b0.z; b[3] = b0.w;
        b[4] = b1.x; b[5] = b1.y; b[6] = b1.z; b[7] = b1.w;
      } else {
        const float2 b0 = *(const float2*)&Bs[kk][col_t * 2];
        const float2 b1 = *(const float2*)&Bs[kk][BN / 2 + col_t * 2];
        b[0] = b0.x; b[1] = b0.y; b[2] = b1.x; b[3] = b1.y;
      }
      #pragma unroll
      for (int i = 0; i < TM; ++i)
        #pragma unroll
        for (int j = 0; j < TN; ++j)
          acc[i][j] = fmaf(a[i], b[j], acc[i][j]);
    }
    __syncthreads();
  }

  #pragma unroll
  for (int i = 0; i < TM; ++i) {
    int r = m0 + ((i < TMH) ? (row_t * TMH + i) : (BM / 2 + row_t * TMH + (i - TMH)));
    #pragma unroll
    for (int half = 0; half < 2; ++half) {
      int cbase = n0 + half * (BN / 2) + col_t * TNH;
      float* cp = &C[(size_t)r * N + cbase];
      #pragma unroll
      for (int j = 0; j < TNH; ++j) {
        float v = acc[i][half * TNH + j] + bias[cbase + j];
        if (RELU) v = fmaxf(v, 0.f);
        cp[j] = v;
      }
    }
  }
}

// ---------------------------------------------------------------- head (K=64, N=3)
__global__ void head_kernel(const float* __restrict__ dw,
                            const float* __restrict__ wph,
                            const float* __restrict__ bh,
                            float* __restrict__ out) {
  int lane = threadIdx.x & 63;
  int rowLocal = threadIdx.x >> 6;            // 0..3
  int row = blockIdx.x * 4 + rowLocal;
  float d = dw[(size_t)row * 64 + lane];
  float a0 = d * wph[lane * 3 + 0];
  float a1 = d * wph[lane * 3 + 1];
  float a2 = d * wph[lane * 3 + 2];
  for (int off = 32; off > 0; off >>= 1) {
    a0 += __shfl_down(a0, off);
    a1 += __shfl_down(a1, off);
    a2 += __shfl_down(a2, off);
  }
  if (lane == 0) {
    out[(size_t)row * 3 + 0] = a0 + bh[0];
    out[(size_t)row * 3 + 1] = a1 + bh[1];
    out[(size_t)row * 3 + 2] = a2 + bh[2];
  }
}

// ---------------------------------------------------------------- launch
extern "C" void kernel_launch(void* const* d_in, const int* in_sizes, int n_in,
                              void* d_out, int out_size, void* d_ws, size_t ws_size,
                              hipStream_t stream) {
  const float* uv   = (const float*)d_in[0];
  const float* feat = (const float*)d_in[1];
  const float* up   = (const float*)d_in[2];
  const int* sArr[4] = {(const int*)d_in[3], (const int*)d_in[4],
                        (const int*)d_in[5], (const int*)d_in[6]};  // s0..s3

  // workspace layout (floats)
  const size_t SLAB = 8ull * 2048 * 512;     // 8,388,608 floats = 32 MiB
  float* Wf = (float*)d_ws;
  float* S0 = Wf;
  float* S1 = Wf + SLAB;
  float* S2 = Wf + 2 * SLAB;
  float* xs = Wf + 3 * SLAB;                 // B*P*512 = 86016 floats
  int* ib = (int*)(xs + (size_t)B_ * P_ * 512);

  // stage order t=0..3 uses pool graphs row3,row2,row1,row0
  int Vt[4] = {1024, 2048, 4096, 8192};
  int NZ[4] = {3072, 6144, 12288, 24576};
  int* cnt[4]; int* rp[4]; int* co[4]; float* va[4];
  {
    int* pc = ib;
    for (int t = 0; t < 4; ++t) { cnt[t] = pc; pc += Vt[t]; }          // 15360 total
    for (int t = 0; t < 4; ++t) { rp[t] = pc; pc += Vt[t] + 1; }
    for (int t = 0; t < 4; ++t) { co[t] = pc; pc += NZ[t]; }
    float* pv = (float*)pc;
    for (int t = 0; t < 4; ++t) { va[t] = pv; pv += NZ[t]; }
  }

  CsrParams cp;
  for (int t = 0; t < 4; ++t) {
    int i = 3 - t;                            // input level index
    cp.row[t] = (const int*)d_in[7 + 3 * i];
    cp.col[t] = (const int*)d_in[8 + 3 * i];
    cp.val[t] = (const float*)d_in[9 + 3 * i];
    cp.cnt[t] = cnt[t]; cp.rowptr[t] = rp[t];
    cp.colsout[t] = co[t]; cp.valsout[t] = va[t];
    cp.nnz[t] = NZ[t]; cp.V[t] = Vt[t];
  }

  sample_kernel<<<B_ * P_, 256, 0, stream>>>(uv, feat, xs);
  upsample_kernel<<<dim3(512, B_), 128, 0, stream>>>(up, xs, S0);

  hipMemsetAsync(ib, 0, 15360 * sizeof(int), stream);
  count_kernel<<<dim3(96, 4), 256, 0, stream>>>(cp);
  scan_kernel<<<4, 256, 0, stream>>>(cp);
  fill_kernel<<<dim3(96, 4), 256, 0, stream>>>(cp);

  struct Stg { int Vin, Vout, Cin, Cout; const int* s; const float *wd, *wp, *bias; };
  Stg st[4] = {
    {512, 1024, 512, 512, sArr[3], (const float*)d_in[19], (const float*)d_in[20], (const float*)d_in[21]},
    {1024, 2048, 512, 256, sArr[2], (const float*)d_in[22], (const float*)d_in[23], (const float*)d_in[24]},
    {2048, 4096, 256, 128, sArr[1], (const float*)d_in[25], (const float*)d_in[26], (const float*)d_in[27]},
    {4096, 8192, 128, 64, sArr[0], (const float*)d_in[28], (const float*)d_in[29], (const float*)d_in[30]},
  };

  for (int t = 0; t < 4; ++t) {
    int lanes = st[t].Cin / 4;
    int rpb = 128 / lanes;
    pool_kernel<<<dim3(st[t].Vout / rpb, B_), 128, 0, stream>>>(
        S0, rp[t], co[t], va[t], S1, st[t].Vout, st[t].Vin, st[t].Cin);
    dw_kernel<<<dim3(st[t].Vout / rpb, B_), 128, 0, stream>>>(
        S1, st[t].s, st[t].wd, S2, st[t].Vout, st[t].Cin);
    int M = B_ * st[t].Vout;
    if (st[t].Cout >= 128) {
      gemm_bias<128, 128, 16, 8, 8, true><<<dim3(M / 128, st[t].Cout / 128), 256, 0, stream>>>(
          S2, st[t].wp, st[t].bias, S0, M, st[t].Cout, st[t].Cin);
    } else {
      gemm_bias<128, 64, 16, 8, 4, true><<<dim3(M / 128, st[t].Cout / 64), 256, 0, stream>>>(
          S2, st[t].wp, st[t].bias, S0, M, st[t].Cout, st[t].Cin);
    }
  }

  // head: dw with s0 on x4 (8,8192,64), then (64x3) projection
  dw_kernel<<<dim3(8192 / 8, B_), 128, 0, stream>>>(
      S0, sArr[0], (const float*)d_in[31], S1, 8192, 64);
  head_kernel<<<(B_ * 8192) / 4, 256, 0, stream>>>(
      S1, (const float*)d_in[32], (const float*)d_in[33], (float*)d_out);
}

// Round 2
// 437.122 us; speedup vs baseline: 1.1095x; 1.1095x over previous
//
#include <hip/hip_runtime.h>

#define B_  8
#define P_  21
#define H_  32
#define W_  32

// ---------------------------------------------------------------- CSR build
struct CsrParams {
  const int*   row[4];
  const int*   col[4];
  const float* val[4];
  int*   cnt[4];
  int*   rowptr[4];
  int*   colsout[4];
  float* valsout[4];
  int    nnz[4];
  int    V[4];
};

__global__ void count_kernel(CsrParams p) {
  int l = blockIdx.y;
  int k = blockIdx.x * 256 + threadIdx.x;
  if (k < p.nnz[l]) atomicAdd(&p.cnt[l][p.row[l][k]], 1);
}

__global__ void scan_kernel(CsrParams p) {
  int l = blockIdx.x;
  int V = p.V[l];
  int* cnt = p.cnt[l];
  int* rp  = p.rowptr[l];
  int t = threadIdx.x;
  int chunk = V / 256;            // 4,8,16,32 — exact
  int base = t * chunk;
  int s = 0;
  for (int i = 0; i < chunk; ++i) s += cnt[base + i];
  __shared__ int sm[256];
  sm[t] = s;
  __syncthreads();
  for (int off = 1; off < 256; off <<= 1) {
    int v = (t >= off) ? sm[t - off] : 0;
    __syncthreads();
    sm[t] += v;
    __syncthreads();
  }
  int run = sm[t] - s;            // exclusive prefix
  for (int i = 0; i < chunk; ++i) {
    int c = cnt[base + i];
    rp[base + i]  = run;
    cnt[base + i] = run;          // becomes fill cursor
    run += c;
  }
  if (t == 255) rp[V] = run;      // == nnz
}

__global__ void fill_kernel(CsrParams p) {
  int l = blockIdx.y;
  int k = blockIdx.x * 256 + threadIdx.x;
  if (k < p.nnz[l]) {
    int r = p.row[l][k];
    int pos = atomicAdd(&p.cnt[l][r], 1);
    p.colsout[l][pos] = p.col[l][k];
    p.valsout[l][pos] = p.val[l][k];
  }
}

// ---------------------------------------------------------------- sampling
__global__ void sample_kernel(const float* __restrict__ uv,
                              const float* __restrict__ feat,
                              float* __restrict__ xs) {
  int bp = blockIdx.x;            // b*21+p
  int b  = bp / P_;
  float u0 = uv[bp * 2 + 0], u1 = uv[bp * 2 + 1];
  float gx = fminf(fmaxf((u0 - 0.5f) * 2.0f, -1.0f), 1.0f);
  float gy = fminf(fmaxf((u1 - 0.5f) * 2.0f, -1.0f), 1.0f);
  float fx = (gx + 1.0f) * 0.5f * (W_ - 1);
  float fy = (gy + 1.0f) * 0.5f * (H_ - 1);
  float x0f = floorf(fx), y0f = floorf(fy);
  float wx = fx - x0f, wy = fy - y0f;
  int x0 = (int)x0f, y0 = (int)y0f;
  int x0i = min(max(x0, 0), W_ - 1), x1i = min(max(x0 + 1, 0), W_ - 1);
  int y0i = min(max(y0, 0), H_ - 1), y1i = min(max(y0 + 1, 0), H_ - 1);
  float w00 = (1.f - wy) * (1.f - wx), w01 = (1.f - wy) * wx;
  float w10 = wy * (1.f - wx),        w11 = wy * wx;
  for (int c = threadIdx.x; c < 512; c += blockDim.x) {
    const float* fb = feat + ((size_t)(b * 512 + c)) * (H_ * W_);
    float v = fb[y0i * W_ + x0i] * w00 + fb[y0i * W_ + x1i] * w01 +
              fb[y1i * W_ + x0i] * w10 + fb[y1i * W_ + x1i] * w11;
    xs[(size_t)bp * 512 + c] = v;
  }
}

__global__ void upsample_kernel(const float* __restrict__ up,
                                const float* __restrict__ xs,
                                float* __restrict__ xu) {
  int v = blockIdx.x, b = blockIdx.y;
  int c4 = threadIdx.x << 2;      // 128 threads * 4 = 512
  float4 acc = make_float4(0.f, 0.f, 0.f, 0.f);
  for (int p = 0; p < P_; ++p) {
    float u = up[v * P_ + p];
    const float4 xv = *(const float4*)&xs[((size_t)(b * P_ + p)) * 512 + c4];
    acc.x = fmaf(u, xv.x, acc.x);
    acc.y = fmaf(u, xv.y, acc.y);
    acc.z = fmaf(u, xv.z, acc.z);
    acc.w = fmaf(u, xv.w, acc.w);
  }
  *(float4*)&xu[((size_t)(b * 512 + v)) * 512 + c4] = acc;
}

// ---------------------------------------------------------------- pool (CSR gather)
__global__ void pool_kernel(const float* __restrict__ x,
                            const int* __restrict__ rowptr,
                            const int* __restrict__ cols,
                            const float* __restrict__ vals,
                            float* __restrict__ out,
                            int Vout, int Vin, int Cin) {
  int lanes = Cin >> 2;
  int lshift = 31 - __clz(lanes);
  int rpb = 128 >> lshift;
  int lr = threadIdx.x >> lshift;
  int lc = threadIdx.x & (lanes - 1);
  int n = blockIdx.x * rpb + lr;
  int b = blockIdx.y;
  int c4 = lc << 2;
  int j0 = rowptr[n], j1 = rowptr[n + 1];
  float4 acc = make_float4(0.f, 0.f, 0.f, 0.f);
  for (int j = j0; j < j1; ++j) {
    int src = cols[j];
    float v = vals[j];
    const float4 xv = *(const float4*)&x[((size_t)b * Vin + src) * Cin + c4];
    acc.x = fmaf(v, xv.x, acc.x);
    acc.y = fmaf(v, xv.y, acc.y);
    acc.z = fmaf(v, xv.z, acc.z);
    acc.w = fmaf(v, xv.w, acc.w);
  }
  *(float4*)&out[((size_t)b * Vout + n) * Cin + c4] = acc;
}

// ---------------------------------------------------------------- depthwise gather
__global__ void dw_kernel(const float* __restrict__ xin,
                          const int* __restrict__ sidx,
                          const float* __restrict__ wd,
                          float* __restrict__ out,
                          int Vout, int Cin) {
  int lanes = Cin >> 2;
  int lshift = 31 - __clz(lanes);
  int rpb = 128 >> lshift;
  int lr = threadIdx.x >> lshift;
  int lc = threadIdx.x & (lanes - 1);
  int n = blockIdx.x * rpb + lr;
  int b = blockIdx.y;
  int c4 = lc << 2;
  float4 acc = make_float4(0.f, 0.f, 0.f, 0.f);
  #pragma unroll
  for (int s = 0; s < 9; ++s) {
    int r = sidx[n * 9 + s];
    const float4 wv = *(const float4*)&wd[s * Cin + c4];
    const float4 xv = *(const float4*)&xin[((size_t)b * Vout + r) * Cin + c4];
    acc.x = fmaf(wv.x, xv.x, acc.x);
    acc.y = fmaf(wv.y, xv.y, acc.y);
    acc.z = fmaf(wv.z, xv.z, acc.z);
    acc.w = fmaf(wv.w, xv.w, acc.w);
  }
  *(float4*)&out[((size_t)b * Vout + n) * Cin + c4] = acc;
}

// ---------------------------------------------------------------- fp32 GEMM + bias (+relu)
// 128x64 tile, TM=8 x TN=4 per thread, 256 threads -> 2 blocks/CU, 8 waves/CU
template <int BM, int BN, int BK, int TM, int TN, bool RELU>
__launch_bounds__(256)
__global__ void gemm_bias(const float* __restrict__ A,   // M x K
                          const float* __restrict__ Bw,  // K x N
                          const float* __restrict__ bias,
                          float* __restrict__ C,         // M x N
                          int M, int N, int K) {
  static_assert(TM == 8, "TM fixed at 8");
  constexpr int TMH = TM / 2;
  constexpr int TNH = TN / 2;
  constexpr int NTX = BN / TN;     // 16 for both configs
  __shared__ float As[BK][BM + 4];
  __shared__ float Bs[BK][BN];
  const int tid   = threadIdx.x;
  const int col_t = tid % NTX;
  const int row_t = tid / NTX;
  const int m0 = blockIdx.x * BM;
  const int n0 = blockIdx.y * BN;

  float acc[TM][TN];
  #pragma unroll
  for (int i = 0; i < TM; ++i)
    #pragma unroll
    for (int j = 0; j < TN; ++j) acc[i][j] = 0.f;

  for (int k0 = 0; k0 < K; k0 += BK) {
    // stage A tile (transpose into As[k][m])
    #pragma unroll
    for (int l = tid; l < BM * BK / 4; l += 256) {
      int row = l >> 2;           // BK/4 == 4
      int kq  = l & 3;
      const float4 v = *(const float4*)&A[(size_t)(m0 + row) * K + k0 + (kq << 2)];
      As[kq * 4 + 0][row] = v.x;
      As[kq * 4 + 1][row] = v.y;
      As[kq * 4 + 2][row] = v.z;
      As[kq * 4 + 3][row] = v.w;
    }
    // stage B tile (direct)
    #pragma unroll
    for (int l = tid; l < BK * BN / 4; l += 256) {
      int row = l / (BN / 4);
      int cq  = l % (BN / 4);
      *(float4*)&Bs[row][cq * 4] =
          *(const float4*)&Bw[(size_t)(k0 + row) * N + n0 + cq * 4];
    }
    __syncthreads();
    #pragma unroll
    for (int kk = 0; kk < BK; ++kk) {
      float a[TM], b[TN];
      const float4 a0 = *(const float4*)&As[kk][row_t * TMH];
      const float4 a1 = *(const float4*)&As[kk][BM / 2 + row_t * TMH];
      a[0] = a0.x; a[1] = a0.y; a[2] = a0.z; a[3] = a0.w;
      a[4] = a1.x; a[5] = a1.y; a[6] = a1.z; a[7] = a1.w;
      if constexpr (TNH == 4) {
        const float4 b0 = *(const float4*)&Bs[kk][col_t * 4];
        const float4 b1 = *(const float4*)&Bs[kk][BN / 2 + col_t * 4];
        b[0] = b0.x; b[1] = b0.y; b[2] = b0.z; b[3] = b0.w;
        b[4] = b1.x; b[5] = b1.y; b[6] = b1.z; b[7] = b1.w;
      } else {
        const float2 b0 = *(const float2*)&Bs[kk][col_t * 2];
        const float2 b1 = *(const float2*)&Bs[kk][BN / 2 + col_t * 2];
        b[0] = b0.x; b[1] = b0.y; b[2] = b1.x; b[3] = b1.y;
      }
      #pragma unroll
      for (int i = 0; i < TM; ++i)
        #pragma unroll
        for (int j = 0; j < TN; ++j)
          acc[i][j] = fmaf(a[i], b[j], acc[i][j]);
    }
    __syncthreads();
  }

  #pragma unroll
  for (int i = 0; i < TM; ++i) {
    int r = m0 + ((i < TMH) ? (row_t * TMH + i) : (BM / 2 + row_t * TMH + (i - TMH)));
    #pragma unroll
    for (int half = 0; half < 2; ++half) {
      int cbase = n0 + half * (BN / 2) + col_t * TNH;
      float* cp = &C[(size_t)r * N + cbase];
      #pragma unroll
      for (int j = 0; j < TNH; ++j) {
        float v = acc[i][half * TNH + j] + bias[cbase + j];
        if (RELU) v = fmaxf(v, 0.f);
        cp[j] = v;
      }
    }
  }
}

// ---------------------------------------------------------------- head (K=64, N=3)
__global__ void head_kernel(const float* __restrict__ dw,
                            const float* __restrict__ wph,
                            const float* __restrict__ bh,
                            float* __restrict__ out) {
  int lane = threadIdx.x & 63;
  int rowLocal = threadIdx.x >> 6;            // 0..3
  int row = blockIdx.x * 4 + rowLocal;
  float d = dw[(size_t)row * 64 + lane];
  float a0 = d * wph[lane * 3 + 0];
  float a1 = d * wph[lane * 3 + 1];
  float a2 = d * wph[lane * 3 + 2];
  for (int off = 32; off > 0; off >>= 1) {
    a0 += __shfl_down(a0, off);
    a1 += __shfl_down(a1, off);
    a2 += __shfl_down(a2, off);
  }
  if (lane == 0) {
    out[(size_t)row * 3 + 0] = a0 + bh[0];
    out[(size_t)row * 3 + 1] = a1 + bh[1];
    out[(size_t)row * 3 + 2] = a2 + bh[2];
  }
}

// ---------------------------------------------------------------- launch
extern "C" void kernel_launch(void* const* d_in, const int* in_sizes, int n_in,
                              void* d_out, int out_size, void* d_ws, size_t ws_size,
                              hipStream_t stream) {
  const float* uv   = (const float*)d_in[0];
  const float* feat = (const float*)d_in[1];
  const float* up   = (const float*)d_in[2];
  const int* sArr[4] = {(const int*)d_in[3], (const int*)d_in[4],
                        (const int*)d_in[5], (const int*)d_in[6]};  // s0..s3

  // workspace layout (floats)
  const size_t SLAB = 8ull * 2048 * 512;     // 8,388,608 floats = 32 MiB
  float* Wf = (float*)d_ws;
  float* S0 = Wf;
  float* S1 = Wf + SLAB;
  float* S2 = Wf + 2 * SLAB;
  float* xs = Wf + 3 * SLAB;                 // B*P*512 = 86016 floats
  int* ib = (int*)(xs + (size_t)B_ * P_ * 512);

  // stage order t=0..3 uses pool graphs row3,row2,row1,row0
  int Vt[4] = {1024, 2048, 4096, 8192};
  int NZ[4] = {3072, 6144, 12288, 24576};
  int* cnt[4]; int* rp[4]; int* co[4]; float* va[4];
  {
    int* pc = ib;
    for (int t = 0; t < 4; ++t) { cnt[t] = pc; pc += Vt[t]; }          // 15360 total
    for (int t = 0; t < 4; ++t) { rp[t] = pc; pc += Vt[t] + 1; }
    for (int t = 0; t < 4; ++t) { co[t] = pc; pc += NZ[t]; }
    float* pv = (float*)pc;
    for (int t = 0; t < 4; ++t) { va[t] = pv; pv += NZ[t]; }
  }

  CsrParams cp;
  for (int t = 0; t < 4; ++t) {
    int i = 3 - t;                            // input level index
    cp.row[t] = (const int*)d_in[7 + 3 * i];
    cp.col[t] = (const int*)d_in[8 + 3 * i];
    cp.val[t] = (const float*)d_in[9 + 3 * i];
    cp.cnt[t] = cnt[t]; cp.rowptr[t] = rp[t];
    cp.colsout[t] = co[t]; cp.valsout[t] = va[t];
    cp.nnz[t] = NZ[t]; cp.V[t] = Vt[t];
  }

  sample_kernel<<<B_ * P_, 256, 0, stream>>>(uv, feat, xs);
  upsample_kernel<<<dim3(512, B_), 128, 0, stream>>>(up, xs, S0);

  hipMemsetAsync(ib, 0, 15360 * sizeof(int), stream);
  count_kernel<<<dim3(96, 4), 256, 0, stream>>>(cp);
  scan_kernel<<<4, 256, 0, stream>>>(cp);
  fill_kernel<<<dim3(96, 4), 256, 0, stream>>>(cp);

  struct Stg { int Vin, Vout, Cin, Cout; const int* s; const float *wd, *wp, *bias; };
  Stg st[4] = {
    {512, 1024, 512, 512, sArr[3], (const float*)d_in[19], (const float*)d_in[20], (const float*)d_in[21]},
    {1024, 2048, 512, 256, sArr[2], (const float*)d_in[22], (const float*)d_in[23], (const float*)d_in[24]},
    {2048, 4096, 256, 128, sArr[1], (const float*)d_in[25], (const float*)d_in[26], (const float*)d_in[27]},
    {4096, 8192, 128, 64, sArr[0], (const float*)d_in[28], (const float*)d_in[29], (const float*)d_in[30]},
  };

  for (int t = 0; t < 4; ++t) {
    int lanes = st[t].Cin / 4;
    int rpb = 128 / lanes;
    pool_kernel<<<dim3(st[t].Vout / rpb, B_), 128, 0, stream>>>(
        S0, rp[t], co[t], va[t], S1, st[t].Vout, st[t].Vin, st[t].Cin);
    dw_kernel<<<dim3(st[t].Vout / rpb, B_), 128, 0, stream>>>(
        S1, st[t].s, st[t].wd, S2, st[t].Vout, st[t].Cin);
    int M = B_ * st[t].Vout;
    // 128x64 tile everywhere: grid = 512 blocks for every stage -> 8 waves/CU
    gemm_bias<128, 64, 16, 8, 4, true><<<dim3(M / 128, st[t].Cout / 64), 256, 0, stream>>>(
        S2, st[t].wp, st[t].bias, S0, M, st[t].Cout, st[t].Cin);
  }

  // head: dw with s0 on x4 (8,8192,64), then (64x3) projection
  dw_kernel<<<dim3(8192 / 8, B_), 128, 0, stream>>>(
      S0, sArr[0], (const float*)d_in[31], S1, 8192, 64);
  head_kernel<<<(B_ * 8192) / 4, 256, 0, stream>>>(
      S1, (const float*)d_in[32], (const float*)d_in[33], (float*)d_out);
}

// Round 3
// 331.112 us; speedup vs baseline: 1.4648x; 1.3202x over previous
//
#include <hip/hip_runtime.h>

#define B_  8
#define P_  21
#define H_  32
#define W_  32

typedef float f32x4 __attribute__((ext_vector_type(4)));
typedef _Float16 f16x8 __attribute__((ext_vector_type(8)));
struct h4 { _Float16 x, y, z, w; };

// ---------------------------------------------------------------- CSR build
struct CsrParams {
  const int*   row[4];
  const int*   col[4];
  const float* val[4];
  int*   cnt[4];
  int*   rowptr[4];
  int*   colsout[4];
  float* valsout[4];
  int    nnz[4];
  int    V[4];
};

__global__ void count_kernel(CsrParams p) {
  int l = blockIdx.y;
  int k = blockIdx.x * 256 + threadIdx.x;
  if (k < p.nnz[l]) atomicAdd(&p.cnt[l][p.row[l][k]], 1);
}

__global__ void scan_kernel(CsrParams p) {
  int l = blockIdx.x;
  int V = p.V[l];
  int* cnt = p.cnt[l];
  int* rp  = p.rowptr[l];
  int t = threadIdx.x;
  int chunk = V / 256;
  int base = t * chunk;
  int s = 0;
  for (int i = 0; i < chunk; ++i) s += cnt[base + i];
  __shared__ int sm[256];
  sm[t] = s;
  __syncthreads();
  for (int off = 1; off < 256; off <<= 1) {
    int v = (t >= off) ? sm[t - off] : 0;
    __syncthreads();
    sm[t] += v;
    __syncthreads();
  }
  int run = sm[t] - s;
  for (int i = 0; i < chunk; ++i) {
    int c = cnt[base + i];
    rp[base + i]  = run;
    cnt[base + i] = run;
    run += c;
  }
  if (t == 255) rp[V] = run;
}

__global__ void fill_kernel(CsrParams p) {
  int l = blockIdx.y;
  int k = blockIdx.x * 256 + threadIdx.x;
  if (k < p.nnz[l]) {
    int r = p.row[l][k];
    int pos = atomicAdd(&p.cnt[l][r], 1);
    p.colsout[l][pos] = p.col[l][k];
    p.valsout[l][pos] = p.val[l][k];
  }
}

// ---------------------------------------------------------------- sampling
__global__ void sample_kernel(const float* __restrict__ uv,
                              const float* __restrict__ feat,
                              float* __restrict__ xs) {
  int bp = blockIdx.x;
  int b  = bp / P_;
  float u0 = uv[bp * 2 + 0], u1 = uv[bp * 2 + 1];
  float gx = fminf(fmaxf((u0 - 0.5f) * 2.0f, -1.0f), 1.0f);
  float gy = fminf(fmaxf((u1 - 0.5f) * 2.0f, -1.0f), 1.0f);
  float fx = (gx + 1.0f) * 0.5f * (W_ - 1);
  float fy = (gy + 1.0f) * 0.5f * (H_ - 1);
  float x0f = floorf(fx), y0f = floorf(fy);
  float wx = fx - x0f, wy = fy - y0f;
  int x0 = (int)x0f, y0 = (int)y0f;
  int x0i = min(max(x0, 0), W_ - 1), x1i = min(max(x0 + 1, 0), W_ - 1);
  int y0i = min(max(y0, 0), H_ - 1), y1i = min(max(y0 + 1, 0), H_ - 1);
  float w00 = (1.f - wy) * (1.f - wx), w01 = (1.f - wy) * wx;
  float w10 = wy * (1.f - wx),        w11 = wy * wx;
  for (int c = threadIdx.x; c < 512; c += blockDim.x) {
    const float* fb = feat + ((size_t)(b * 512 + c)) * (H_ * W_);
    float v = fb[y0i * W_ + x0i] * w00 + fb[y0i * W_ + x1i] * w01 +
              fb[y1i * W_ + x0i] * w10 + fb[y1i * W_ + x1i] * w11;
    xs[(size_t)bp * 512 + c] = v;
  }
}

__global__ void upsample_kernel(const float* __restrict__ up,
                                const float* __restrict__ xs,
                                float* __restrict__ xu) {
  int v = blockIdx.x, b = blockIdx.y;
  int c4 = threadIdx.x << 2;
  float4 acc = make_float4(0.f, 0.f, 0.f, 0.f);
  for (int p = 0; p < P_; ++p) {
    float u = up[v * P_ + p];
    const float4 xv = *(const float4*)&xs[((size_t)(b * P_ + p)) * 512 + c4];
    acc.x = fmaf(u, xv.x, acc.x);
    acc.y = fmaf(u, xv.y, acc.y);
    acc.z = fmaf(u, xv.z, acc.z);
    acc.w = fmaf(u, xv.w, acc.w);
  }
  *(float4*)&xu[((size_t)(b * 512 + v)) * 512 + c4] = acc;
}

// ---------------------------------------------------------------- pool (CSR gather)
__global__ void pool_kernel(const float* __restrict__ x,
                            const int* __restrict__ rowptr,
                            const int* __restrict__ cols,
                            const float* __restrict__ vals,
                            float* __restrict__ out,
                            int Vout, int Vin, int Cin) {
  int lanes = Cin >> 2;
  int lshift = 31 - __clz(lanes);
  int rpb = 128 >> lshift;
  int lr = threadIdx.x >> lshift;
  int lc = threadIdx.x & (lanes - 1);
  int n = blockIdx.x * rpb + lr;
  int b = blockIdx.y;
  int c4 = lc << 2;
  int j0 = rowptr[n], j1 = rowptr[n + 1];
  float4 acc = make_float4(0.f, 0.f, 0.f, 0.f);
  for (int j = j0; j < j1; ++j) {
    int src = cols[j];
    float v = vals[j];
    const float4 xv = *(const float4*)&x[((size_t)b * Vin + src) * Cin + c4];
    acc.x = fmaf(v, xv.x, acc.x);
    acc.y = fmaf(v, xv.y, acc.y);
    acc.z = fmaf(v, xv.z, acc.z);
    acc.w = fmaf(v, xv.w, acc.w);
  }
  *(float4*)&out[((size_t)b * Vout + n) * Cin + c4] = acc;
}

// ---------------------------------------------------------------- depthwise gather + f16x2 split
__global__ void dw_split_kernel(const float* __restrict__ xin,
                                const int* __restrict__ sidx,
                                const float* __restrict__ wd,
                                _Float16* __restrict__ a0o,
                                _Float16* __restrict__ a1o,
                                int Vout, int Cin) {
  int lanes = Cin >> 2;
  int lshift = 31 - __clz(lanes);
  int rpb = 128 >> lshift;
  int lr = threadIdx.x >> lshift;
  int lc = threadIdx.x & (lanes - 1);
  int n = blockIdx.x * rpb + lr;
  int b = blockIdx.y;
  int c4 = lc << 2;
  float4 acc = make_float4(0.f, 0.f, 0.f, 0.f);
  #pragma unroll
  for (int s = 0; s < 9; ++s) {
    int r = sidx[n * 9 + s];
    const float4 wv = *(const float4*)&wd[s * Cin + c4];
    const float4 xv = *(const float4*)&xin[((size_t)b * Vout + r) * Cin + c4];
    acc.x = fmaf(wv.x, xv.x, acc.x);
    acc.y = fmaf(wv.y, xv.y, acc.y);
    acc.z = fmaf(wv.z, xv.z, acc.z);
    acc.w = fmaf(wv.w, xv.w, acc.w);
  }
  size_t m = (size_t)b * Vout + n;
  float v[4] = {acc.x, acc.y, acc.z, acc.w};
  h4 p0, p1;
  _Float16* q0 = &p0.x;
  _Float16* q1 = &p1.x;
  #pragma unroll
  for (int i = 0; i < 4; ++i) {
    _Float16 h0 = (_Float16)v[i];
    float r = (v[i] - (float)h0) * 2048.0f;   // exact pow2 scale keeps lo-plane normal
    q0[i] = h0;
    q1[i] = (_Float16)r;
  }
  *(h4*)&a0o[m * Cin + c4] = p0;
  *(h4*)&a1o[m * Cin + c4] = p1;
}

// ---------------------------------------------------------------- B split: wp (K x N) -> Bt planes (N x K)
__global__ void bsplit_kernel(const float* __restrict__ wp,
                              _Float16* __restrict__ b0,
                              _Float16* __restrict__ b1,
                              int K, int N) {
  int idx = blockIdx.x * 256 + threadIdx.x;
  if (idx >= N * K) return;
  int n = idx / K, k = idx - n * K;
  float v = wp[(size_t)k * N + n];
  _Float16 h0 = (_Float16)v;
  float r = (v - (float)h0) * 2048.0f;
  b0[idx] = h0;
  b1[idx] = (_Float16)r;
}

// ---------------------------------------------------------------- f16x2-split MFMA GEMM + bias + relu
// C(MxN,f32) = A(MxK) * B(KxN) with A=A0+A1/2048, B=B0+B1/2048 (f16 planes),
// dropping A1*B1 (~2^-22 rel). B planes stored transposed (N x K).
// BM=128, BN=64, BK=64; 256 thr = 4 waves (2x2), wave tile 64x32, mfma 16x16x32.
__global__ __launch_bounds__(256) void gemm_f16x2(
    const _Float16* __restrict__ A0, const _Float16* __restrict__ A1,
    const _Float16* __restrict__ Bt0, const _Float16* __restrict__ Bt1,
    const float* __restrict__ bias, float* __restrict__ C,
    int M, int N, int K) {
  constexpr int RP = 72;                    // 64 + 8 halves pad (16B-aligned rows)
  __shared__ _Float16 As[2][128][RP];       // 36.9 KB
  __shared__ _Float16 Bs[2][64][RP];        // 18.4 KB
  const int tid = threadIdx.x;
  const int m0 = blockIdx.x * 128, n0 = blockIdx.y * 64;
  const int wid = tid >> 6, lane = tid & 63;
  const int wr = wid >> 1, wc = wid & 1;
  const int lo = lane & 15, hi = lane >> 4;

  f32x4 accM[4][2], accC[4][2];
  #pragma unroll
  for (int mi = 0; mi < 4; ++mi)
    #pragma unroll
    for (int nj = 0; nj < 2; ++nj) {
      accM[mi][nj] = (f32x4){0.f, 0.f, 0.f, 0.f};
      accC[mi][nj] = (f32x4){0.f, 0.f, 0.f, 0.f};
    }

  const _Float16* gA[2] = {A0, A1};
  const _Float16* gB[2] = {Bt0, Bt1};

  for (int k0 = 0; k0 < K; k0 += 64) {
    #pragma unroll
    for (int p = 0; p < 2; ++p) {
      #pragma unroll
      for (int i = 0; i < 4; ++i) {          // A plane: 1024 chunks of 8 halves
        int c = tid + 256 * i;
        int r = c >> 3, k8 = (c & 7) << 3;
        uint4 v = *(const uint4*)(gA[p] + (size_t)(m0 + r) * K + k0 + k8);
        *(uint4*)&As[p][r][k8] = v;
      }
      #pragma unroll
      for (int i = 0; i < 2; ++i) {          // B plane: 512 chunks
        int c = tid + 256 * i;
        int r = c >> 3, k8 = (c & 7) << 3;
        uint4 v = *(const uint4*)(gB[p] + (size_t)(n0 + r) * K + k0 + k8);
        *(uint4*)&Bs[p][r][k8] = v;
      }
    }
    __syncthreads();
    #pragma unroll
    for (int s = 0; s < 2; ++s) {
      const int kk = s * 32 + hi * 8;
      f16x8 af[4][2], bf[2][2];
      #pragma unroll
      for (int mi = 0; mi < 4; ++mi) {
        af[mi][0] = *(const f16x8*)&As[0][wr * 64 + mi * 16 + lo][kk];
        af[mi][1] = *(const f16x8*)&As[1][wr * 64 + mi * 16 + lo][kk];
      }
      #pragma unroll
      for (int nj = 0; nj < 2; ++nj) {
        bf[nj][0] = *(const f16x8*)&Bs[0][wc * 32 + nj * 16 + lo][kk];
        bf[nj][1] = *(const f16x8*)&Bs[1][wc * 32 + nj * 16 + lo][kk];
      }
      #pragma unroll
      for (int mi = 0; mi < 4; ++mi)
        #pragma unroll
        for (int nj = 0; nj < 2; ++nj) {
          accM[mi][nj] = __builtin_amdgcn_mfma_f32_16x16x32_f16(
              af[mi][0], bf[nj][0], accM[mi][nj], 0, 0, 0);
          accC[mi][nj] = __builtin_amdgcn_mfma_f32_16x16x32_f16(
              af[mi][0], bf[nj][1], accC[mi][nj], 0, 0, 0);
          accC[mi][nj] = __builtin_amdgcn_mfma_f32_16x16x32_f16(
              af[mi][1], bf[nj][0], accC[mi][nj], 0, 0, 0);
        }
    }
    __syncthreads();
  }

  const float INV = 1.0f / 2048.0f;
  #pragma unroll
  for (int mi = 0; mi < 4; ++mi)
    #pragma unroll
    for (int nj = 0; nj < 2; ++nj) {
      int col = n0 + wc * 32 + nj * 16 + lo;
      float bv = bias[col];
      #pragma unroll
      for (int r = 0; r < 4; ++r) {
        int row = m0 + wr * 64 + mi * 16 + hi * 4 + r;
        float v = accM[mi][nj][r] + accC[mi][nj][r] * INV + bv;
        v = fmaxf(v, 0.f);
        C[(size_t)row * N + col] = v;
      }
    }
}

// ---------------------------------------------------------------- head depthwise (fp32) + projection
__global__ void dw_kernel(const float* __restrict__ xin,
                          const int* __restrict__ sidx,
                          const float* __restrict__ wd,
                          float* __restrict__ out,
                          int Vout, int Cin) {
  int lanes = Cin >> 2;
  int lshift = 31 - __clz(lanes);
  int rpb = 128 >> lshift;
  int lr = threadIdx.x >> lshift;
  int lc = threadIdx.x & (lanes - 1);
  int n = blockIdx.x * rpb + lr;
  int b = blockIdx.y;
  int c4 = lc << 2;
  float4 acc = make_float4(0.f, 0.f, 0.f, 0.f);
  #pragma unroll
  for (int s = 0; s < 9; ++s) {
    int r = sidx[n * 9 + s];
    const float4 wv = *(const float4*)&wd[s * Cin + c4];
    const float4 xv = *(const float4*)&xin[((size_t)b * Vout + r) * Cin + c4];
    acc.x = fmaf(wv.x, xv.x, acc.x);
    acc.y = fmaf(wv.y, xv.y, acc.y);
    acc.z = fmaf(wv.z, xv.z, acc.z);
    acc.w = fmaf(wv.w, xv.w, acc.w);
  }
  *(float4*)&out[((size_t)b * Vout + n) * Cin + c4] = acc;
}

__global__ void head_kernel(const float* __restrict__ dw,
                            const float* __restrict__ wph,
                            const float* __restrict__ bh,
                            float* __restrict__ out) {
  int lane = threadIdx.x & 63;
  int rowLocal = threadIdx.x >> 6;
  int row = blockIdx.x * 4 + rowLocal;
  float d = dw[(size_t)row * 64 + lane];
  float a0 = d * wph[lane * 3 + 0];
  float a1 = d * wph[lane * 3 + 1];
  float a2 = d * wph[lane * 3 + 2];
  for (int off = 32; off > 0; off >>= 1) {
    a0 += __shfl_down(a0, off);
    a1 += __shfl_down(a1, off);
    a2 += __shfl_down(a2, off);
  }
  if (lane == 0) {
    out[(size_t)row * 3 + 0] = a0 + bh[0];
    out[(size_t)row * 3 + 1] = a1 + bh[1];
    out[(size_t)row * 3 + 2] = a2 + bh[2];
  }
}

// ---------------------------------------------------------------- launch
extern "C" void kernel_launch(void* const* d_in, const int* in_sizes, int n_in,
                              void* d_out, int out_size, void* d_ws, size_t ws_size,
                              hipStream_t stream) {
  const float* uv   = (const float*)d_in[0];
  const float* feat = (const float*)d_in[1];
  const float* up   = (const float*)d_in[2];
  const int* sArr[4] = {(const int*)d_in[3], (const int*)d_in[4],
                        (const int*)d_in[5], (const int*)d_in[6]};

  // workspace layout
  const size_t SLAB = 8ull * 2048 * 512;            // 8,388,608 elements
  float* Wf = (float*)d_ws;
  float* S0 = Wf;                                   // fp32 slab (x / gemm out); live region < 4.2M floats
  float* S1 = Wf + SLAB;                            // fp32 slab (pool out)
  _Float16* A0 = (_Float16*)(S1 + SLAB);            // dw hi plane (M x K)
  _Float16* A1 = A0 + SLAB;                         // dw lo plane
  // Bt planes live in the dead upper half of S0 (gemm C <= 4.2M floats)
  _Float16* Bt0 = (_Float16*)(S0 + 4500000);        // 262144 halves max
  _Float16* Bt1 = Bt0 + 262144;
  float* xs = (float*)(A1 + SLAB);                  // B*P*512 = 86016 floats
  int* ib = (int*)(xs + (size_t)B_ * P_ * 512);
  float* HD = (float*)A0;                           // head dw out (4.2M floats) aliases A planes

  int Vt[4] = {1024, 2048, 4096, 8192};
  int NZ[4] = {3072, 6144, 12288, 24576};
  int* cnt[4]; int* rp[4]; int* co[4]; float* va[4];
  {
    int* pc = ib;
    for (int t = 0; t < 4; ++t) { cnt[t] = pc; pc += Vt[t]; }
    for (int t = 0; t < 4; ++t) { rp[t] = pc; pc += Vt[t] + 1; }
    for (int t = 0; t < 4; ++t) { co[t] = pc; pc += NZ[t]; }
    float* pv = (float*)pc;
    for (int t = 0; t < 4; ++t) { va[t] = pv; pv += NZ[t]; }
  }

  CsrParams cp;
  for (int t = 0; t < 4; ++t) {
    int i = 3 - t;
    cp.row[t] = (const int*)d_in[7 + 3 * i];
    cp.col[t] = (const int*)d_in[8 + 3 * i];
    cp.val[t] = (const float*)d_in[9 + 3 * i];
    cp.cnt[t] = cnt[t]; cp.rowptr[t] = rp[t];
    cp.colsout[t] = co[t]; cp.valsout[t] = va[t];
    cp.nnz[t] = NZ[t]; cp.V[t] = Vt[t];
  }

  sample_kernel<<<B_ * P_, 256, 0, stream>>>(uv, feat, xs);
  upsample_kernel<<<dim3(512, B_), 128, 0, stream>>>(up, xs, S0);

  hipMemsetAsync(ib, 0, 15360 * sizeof(int), stream);
  count_kernel<<<dim3(96, 4), 256, 0, stream>>>(cp);
  scan_kernel<<<4, 256, 0, stream>>>(cp);
  fill_kernel<<<dim3(96, 4), 256, 0, stream>>>(cp);

  struct Stg { int Vin, Vout, Cin, Cout; const int* s; const float *wd, *wp, *bias; };
  Stg st[4] = {
    {512, 1024, 512, 512, sArr[3], (const float*)d_in[19], (const float*)d_in[20], (const float*)d_in[21]},
    {1024, 2048, 512, 256, sArr[2], (const float*)d_in[22], (const float*)d_in[23], (const float*)d_in[24]},
    {2048, 4096, 256, 128, sArr[1], (const float*)d_in[25], (const float*)d_in[26], (const float*)d_in[27]},
    {4096, 8192, 128, 64, sArr[0], (const float*)d_in[28], (const float*)d_in[29], (const float*)d_in[30]},
  };

  for (int t = 0; t < 4; ++t) {
    int lanes = st[t].Cin / 4;
    int rpb = 128 / lanes;
    pool_kernel<<<dim3(st[t].Vout / rpb, B_), 128, 0, stream>>>(
        S0, rp[t], co[t], va[t], S1, st[t].Vout, st[t].Vin, st[t].Cin);
    dw_split_kernel<<<dim3(st[t].Vout / rpb, B_), 128, 0, stream>>>(
        S1, st[t].s, st[t].wd, A0, A1, st[t].Vout, st[t].Cin);
    int KK = st[t].Cin, NN = st[t].Cout;
    bsplit_kernel<<<(KK * NN + 255) / 256, 256, 0, stream>>>(
        st[t].wp, Bt0, Bt1, KK, NN);
    int M = B_ * st[t].Vout;
    gemm_f16x2<<<dim3(M / 128, NN / 64), 256, 0, stream>>>(
        A0, A1, Bt0, Bt1, st[t].bias, S0, M, NN, KK);
  }

  // head: fp32 depthwise (K=64) + 64x3 projection
  dw_kernel<<<dim3(8192 / 8, B_), 128, 0, stream>>>(
      S0, sArr[0], (const float*)d_in[31], HD, 8192, 64);
  head_kernel<<<(B_ * 8192) / 4, 256, 0, stream>>>(
      HD, (const float*)d_in[32], (const float*)d_in[33], (float*)d_out);
}